// Round 6
// baseline (440.076 us; speedup 1.0000x reference)
//
#include <hip/hip_runtime.h>
#include <math.h>

// Problem constants: B=32, H=512, N=64, NUM_PROPS=2080
#define PB 32
#define PH 512
#define PN 64
#define PP 2080

// out layout (floats), reference return order:
//   [0,        OFF_MAP)   props_h  (B, P, H)
//   [OFF_MAP,  OFF_MASK)  ori_map_h(B, H, 64, 64)
//   [OFF_MASK, ...)       mask     (B, 1, 64, 64)
#define OFF_MAP  ((size_t)PB * PP * PH)
#define OFF_MASK (OFF_MAP + (size_t)PB * PH * PN * PN)

// Valid (s,e) pairs written by the pyramid (traced from _pool_specs):
//   scale0: d=e-s in [0,15], any s
//   scale1: d in {17,19,...,31} (odd), s even
//   scale2: d in {35,39,...,63} (d%4==3), s%4==0
__device__ __forceinline__ bool pair_valid(int s, int e) {
    int d = e - s;
    if (d < 0) return false;
    if (d <= 15) return true;
    if (d <= 31) return (d & 1) && !(s & 1);
    return d >= 35 && ((d & 3) == 3) && !(s & 3);
}

// Shared LDS buffer: sized for the K2 sparse table (the largest role).
// 12706 floats = 50.82 KB -> 3 blocks/CU for every role.
#define K2_LVL 2112            // 64 * 33 floats per level
#define K2_ZROW 12672          // zero row (33 floats)
#define LDS_FLOATS 12706

// K1 skewed table: slot(k,c) = 65k + c per row, row stride 392.
#define K1_ROWS 8
#define K1_RS 392
#define K1_ZERO 390            // zero slot

// Grid striping: g in [0,2560): g%5==0 -> K2 block g/5 (512), else K1 block
// g/5*4 + g%5 - 1 (2048). g in [2560,2592) -> K3 mask block (32).
#define GRID_BLOCKS 2592

__global__ __launch_bounds__(256) void fused_kernel(const float* __restrict__ x,
                                                    const int* __restrict__ props,
                                                    float* __restrict__ out) {
    __shared__ float Lf[LDS_FLOATS];
    const int tid = threadIdx.x;
    const int g = blockIdx.x;

    if (g < 2560) {
        const int q = g / 5;
        const int r = g - q * 5;
        if (r != 0) {
            // ---------------- K1: ori_map_h, 8 rows per block ----------------
            const int kb = q * 4 + (r - 1);            // 0..2047
            const size_t rowBase = (size_t)kb * K1_ROWS;
            const int wave = tid >> 6;
            const int lane = tid & 63;                 // = e

            // Per-thread metadata for its 16 s-values (same for all 8 rows).
            int a1[16], a2[16];
#pragma unroll
            for (int i = 0; i < 16; ++i) {
                const int s = wave * 16 + i;
                const int e = lane;
                const bool good = pair_valid(s, e);
                const int k = good ? min(31 - __clz(e - s + 1), 5) : 0;
                a1[i] = good ? 65 * k + s : K1_ZERO;
                a2[i] = good ? 65 * k + (e + 1 - (1 << k)) : K1_ZERO;
            }

            // Stage 8 x-rows (level 0) + zero slots.
#pragma unroll
            for (int i = tid; i < K1_ROWS * 64; i += 256) {
                const int rr = i >> 6, c = i & 63;
                Lf[rr * K1_RS + c] = x[rowBase * 64 + i];   // coalesced
            }
            if (tid < K1_ROWS) Lf[tid * K1_RS + K1_ZERO] = 0.0f;
            __syncthreads();

            // Build levels 1..5 (entries past the queried range unread).
#pragma unroll
            for (int k = 1; k <= 5; ++k) {
                const int off = 1 << (k - 1);
#pragma unroll
                for (int i = tid; i < K1_ROWS * 64; i += 256) {
                    const int rr = i >> 6, c = i & 63;
                    const float* Lp = Lf + rr * K1_RS + 65 * (k - 1);
                    Lf[rr * K1_RS + 65 * k + c] = fmaxf(Lp[c], Lp[min(c + off, 63)]);
                }
                __syncthreads();
            }

            // Emit: 8 rows x 16 s-values, 256 B full-line wave stores.
#pragma unroll 2
            for (int rr = 0; rr < K1_ROWS; ++rr) {
                const float* Lr = Lf + rr * K1_RS;
                float* orow = out + OFF_MAP + (rowBase + rr) * 4096 + lane;
#pragma unroll
                for (int i = 0; i < 16; ++i) {
                    orow[(wave * 16 + i) * 64] = fmaxf(Lr[a1[i]], Lr[a2[i]]);
                }
            }
        } else {
            // ---------------- K2: props_h, 32-h tile per block ----------------
            const int b  = q >> 4;
            const int h0 = (q & 15) * 32;

            // Stage x[b, h0:h0+32, :] transposed: xT[n][h] at n*33+h (level 0).
            const float* xb = x + ((size_t)b * PH + h0) * PN;
#pragma unroll
            for (int i = tid; i < 32 * 64; i += 256) {
                const int h = i >> 6, n = i & 63;
                Lf[n * 33 + h] = xb[i];                // coalesced read
            }
            if (tid < 33) Lf[K2_ZROW + tid] = 0.0f;
            __syncthreads();

            // Build levels 1..5.
#pragma unroll 1
            for (int k = 1; k <= 5; ++k) {
                const int off = 1 << (k - 1);
#pragma unroll
                for (int i = tid; i < 64 * 32; i += 256) {
                    const int n = i >> 5, h = i & 31;
                    const float* Lp = Lf + (k - 1) * K2_LVL;
                    Lf[k * K2_LVL + n * 33 + h] =
                        fmaxf(Lp[n * 33 + h], Lp[min(n + off, 63) * 33 + h]);
                }
                __syncthreads();
            }

            // Emit: 2 props per wave step; addr resolved inline from global
            // (props = 8.3 KB, L1-resident; VALU is otherwise idle).
            const int wave = tid >> 6;
            const int sub  = (tid >> 5) & 1;
            const int h    = tid & 31;
            const int2* props2 = (const int2*)props;
            float* ob = out + (size_t)b * PP * PH + h0 + h;
#pragma unroll 4
            for (int i = 0; i < PP / 8; ++i) {         // 260 steps
                const int idx = i * 8 + wave * 2 + sub;
                const int2 pr = props2[idx];           // broadcast, L1-hit
                const int s = pr.x, e1 = pr.y - 1;
                const bool good = pair_valid(s, e1);   // covers e1 < s
                const int k = good ? min(31 - __clz(e1 - s + 1), 5) : 0;
                const int A1 = good ? k * K2_LVL + s * 33 : K2_ZROW;
                const int A2 = good ? k * K2_LVL + (e1 + 1 - (1 << k)) * 33 : K2_ZROW;
                ob[(size_t)idx * PH] = fmaxf(Lf[A1 + h], Lf[A2 + h]);  // 128B lines
            }
        }
    } else {
        // ---------------- K3: mask for one b ----------------
        const int b = g - 2560;

        // Base pattern (b-invariant) in LDS.
        for (int i = tid; i < 4096; i += 256)
            Lf[i] = pair_valid(i >> 6, i & 63) ? 1.0f : 0.0f;
        __syncthreads();

        // Prop scatter on top (races benign: all write 1.0f).
        for (int p = tid; p < PP; p += 256) {
            const int2 pr = ((const int2*)props)[p];
            Lf[pr.x * 64 + (pr.y - 1)] = 1.0f;
        }
        __syncthreads();

        float4* ob = (float4*)(out + OFF_MASK + (size_t)b * 4096);
        const float4* lb = (const float4*)Lf;
#pragma unroll
        for (int i = tid; i < 1024; i += 256)
            ob[i] = lb[i];                             // coalesced float4
    }
}

extern "C" void kernel_launch(void* const* d_in, const int* in_sizes, int n_in,
                              void* d_out, int out_size, void* d_ws, size_t ws_size,
                              hipStream_t stream) {
    const float* x = (const float*)d_in[0];
    const int* props = (const int*)d_in[1];   // integer inputs arrive as int32
    float* out = (float*)d_out;

    fused_kernel<<<GRID_BLOCKS, 256, 0, stream>>>(x, props, out);
}

// Round 7
// 404.975 us; speedup vs baseline: 1.0867x; 1.0867x over previous
//
#include <hip/hip_runtime.h>
#include <math.h>

// Problem constants: B=32, H=512, N=64, NUM_PROPS=2080
#define PB 32
#define PH 512
#define PN 64
#define PP 2080

// out layout (floats), reference return order:
//   [0,        OFF_MAP)   props_h  (B, P, H)
//   [OFF_MAP,  OFF_MASK)  ori_map_h(B, H, 64, 64)
//   [OFF_MASK, ...)       mask     (B, 1, 64, 64)
#define OFF_MAP  ((size_t)PB * PP * PH)
#define OFF_MASK (OFF_MAP + (size_t)PB * PH * PN * PN)

// Valid (s,e) pairs written by the pyramid (traced from _pool_specs):
//   scale0: d=e-s in [0,15], any s
//   scale1: d in {17,19,...,31} (odd), s even
//   scale2: d in {35,39,...,63} (d%4==3), s%4==0
__device__ __forceinline__ bool pair_valid(int s, int e) {
    int d = e - s;
    if (d < 0) return false;
    if (d <= 15) return true;
    if (d <= 31) return (d & 1) && !(s & 1);
    return d >= 35 && ((d & 3) == 3) && !(s & 3);
}

// ---------------------------------------------------------------------------
// Fused single dispatch. LDS = 46.3 KB -> 3 blocks/CU (12 waves/CU; the
// harness fill proves streaming stores saturate at ~3 waves/CU).
// Roles by blockIdx: g<4096: even -> K1 (map), odd -> K2 (props, quartered,
// packed sparse table + LDS addr-pair table — NO global loads in emit loop,
// the R6 mistake). g>=4096 -> K3 (mask, one block per b).
// ---------------------------------------------------------------------------

// K2 packed sparse table (32-h tile, h-stride 33):
//   level k occupies rows [65k-2^k+1, 65k-2^k+1 + (65-2^k)); slot = row*33+h.
//   Total rows 327. Zero row at 327 (float offset 10791). Addr pairs (ints)
//   at 10824 (8B-aligned), 2*520 entries. Total 11864 floats = 46.3 KB.
#define K2_ZSLOT 10791
#define K2_ADDR  10824
#define LDS_FLOATS 11864

// K1 per-row skewed table: row r at r*392, slot(k,c)=65k+c, zero slot 390.
#define K1_ROWS 8
#define K1_RS 392
#define K1_ZERO 390

#define GRID_BLOCKS 4128   // 2048 K1 + 2048 K2 + 32 mask

__global__ __launch_bounds__(256) void fused_kernel(const float* __restrict__ x,
                                                    const int* __restrict__ props,
                                                    float* __restrict__ out) {
    __shared__ float Lf[LDS_FLOATS];
    int* Li = (int*)Lf;
    const int tid = threadIdx.x;
    const int g = blockIdx.x;

    if (g < 4096) {
        if (!(g & 1)) {
            // ---------------- K1: ori_map_h, 8 rows per block ----------------
            const int kb = g >> 1;                      // 0..2047
            const size_t rowBase = (size_t)kb * K1_ROWS;
            const int wave = tid >> 6;
            const int lane = tid & 63;                  // = e

            // Per-thread metadata for its 16 s-values (same for all 8 rows).
            int a1[16], a2[16];
#pragma unroll
            for (int i = 0; i < 16; ++i) {
                const int s = wave * 16 + i;
                const int e = lane;
                const bool good = pair_valid(s, e);
                const int k = good ? min(31 - __clz(e - s + 1), 5) : 0;
                a1[i] = good ? 65 * k + s : K1_ZERO;
                a2[i] = good ? 65 * k + (e + 1 - (1 << k)) : K1_ZERO;
            }

            // Stage 8 x-rows (level 0) + zero slots.
#pragma unroll
            for (int i = tid; i < K1_ROWS * 64; i += 256) {
                const int rr = i >> 6, c = i & 63;
                Lf[rr * K1_RS + c] = x[rowBase * 64 + i];   // coalesced
            }
            if (tid < K1_ROWS) Lf[tid * K1_RS + K1_ZERO] = 0.0f;
            __syncthreads();

            // Build levels 1..5 (entries past the queried range unread).
#pragma unroll
            for (int k = 1; k <= 5; ++k) {
                const int off = 1 << (k - 1);
#pragma unroll
                for (int i = tid; i < K1_ROWS * 64; i += 256) {
                    const int rr = i >> 6, c = i & 63;
                    const float* Lp = Lf + rr * K1_RS + 65 * (k - 1);
                    Lf[rr * K1_RS + 65 * k + c] = fmaxf(Lp[c], Lp[min(c + off, 63)]);
                }
                __syncthreads();
            }

            // Emit: 8 rows x 16 s-values, 256 B full-line wave stores.
            // a1: <=6 distinct addrs on distinct banks (broadcast); a2:
            // stride-1 within k-runs -> conflict-free (R5-verified, -72us).
#pragma unroll 2
            for (int rr = 0; rr < K1_ROWS; ++rr) {
                const float* Lr = Lf + rr * K1_RS;
                float* orow = out + OFF_MAP + (rowBase + rr) * 4096 + lane;
#pragma unroll
                for (int i = 0; i < 16; ++i) {
                    orow[(wave * 16 + i) * 64] = fmaxf(Lr[a1[i]], Lr[a2[i]]);
                }
            }
        } else {
            // ------- K2: props_h, (b, 32-h tile, quarter of 520 props) -------
            const int j  = g >> 1;                      // 0..2047
            const int b  = j >> 6;
            const int h0 = ((j >> 2) & 15) * 32;
            const int p0 = (j & 3) * 520;

            // Stage x[b, h0:h0+32, :] transposed: level 0 = rows 0..63.
            const float* xb = x + ((size_t)b * PH + h0) * PN;
#pragma unroll
            for (int i = tid; i < 32 * 64; i += 256) {
                const int h = i >> 6, n = i & 63;
                Lf[n * 33 + h] = xb[i];                 // coalesced read
            }
            if (tid < 33) Lf[K2_ZSLOT + tid] = 0.0f;

            // Resolve this quarter's props to packed-table addr pairs.
            for (int t = tid; t < 520; t += 256) {
                const int2 pr = ((const int2*)props)[p0 + t];
                const int s = pr.x, e1 = pr.y - 1;
                const bool good = pair_valid(s, e1);    // covers e1 < s
                const int k = good ? min(31 - __clz(e1 - s + 1), 5) : 0;
                const int base = 65 * k - (1 << k) + 1; // packed level offset
                Li[K2_ADDR + 2 * t]     = good ? (base + s) * 33 : K2_ZSLOT;
                Li[K2_ADDR + 2 * t + 1] = good ? (base + e1 + 1 - (1 << k)) * 33 : K2_ZSLOT;
            }
            __syncthreads();

            // Build packed levels 1..5 (level k: 65-2^k rows).
#pragma unroll 1
            for (int k = 1; k <= 5; ++k) {
                const int off   = 1 << (k - 1);
                const int bcur  = 65 * k - (1 << k) + 1;
                const int bprev = 65 * (k - 1) - off + 1;
                const int cnt   = 65 - (1 << k);
                for (int i = tid; i < cnt * 32; i += 256) {
                    const int n = i >> 5, h = i & 31;
                    Lf[(bcur + n) * 33 + h] =
                        fmaxf(Lf[(bprev + n) * 33 + h], Lf[(bprev + n + off) * 33 + h]);
                }
                __syncthreads();
            }

            // Emit: 2 props per wave step, pure-LDS chain (addr pair via
            // ds_read_b64 broadcast + 2 stride-1 table reads) + 128B stores.
            const int wave = tid >> 6;
            const int sub  = (tid >> 5) & 1;
            const int h    = tid & 31;
            float* ob = out + (size_t)b * PP * PH + h0 + h;
#pragma unroll 4
            for (int i = 0; i < 65; ++i) {
                const int idx = i * 8 + wave * 2 + sub;          // 0..519
                const int2 aa = *(const int2*)&Li[K2_ADDR + 2 * idx];
                const float v = fmaxf(Lf[aa.x + h], Lf[aa.y + h]);
                ob[(size_t)(p0 + idx) * PH] = v;
            }
        }
    } else {
        // ---------------- K3: mask for one b ----------------
        const int b = g - 4096;

        // Base pattern (b-invariant) in LDS.
        for (int i = tid; i < 4096; i += 256)
            Lf[i] = pair_valid(i >> 6, i & 63) ? 1.0f : 0.0f;
        __syncthreads();

        // Prop scatter on top (races benign: all write 1.0f).
        for (int p = tid; p < PP; p += 256) {
            const int2 pr = ((const int2*)props)[p];
            Lf[pr.x * 64 + (pr.y - 1)] = 1.0f;
        }
        __syncthreads();

        float4* ob = (float4*)(out + OFF_MASK + (size_t)b * 4096);
        const float4* lb = (const float4*)Lf;
#pragma unroll
        for (int i = tid; i < 1024; i += 256)
            ob[i] = lb[i];                              // coalesced float4
    }
}

extern "C" void kernel_launch(void* const* d_in, const int* in_sizes, int n_in,
                              void* d_out, int out_size, void* d_ws, size_t ws_size,
                              hipStream_t stream) {
    const float* x = (const float*)d_in[0];
    const int* props = (const int*)d_in[1];   // integer inputs arrive as int32
    float* out = (float*)d_out;

    fused_kernel<<<GRID_BLOCKS, 256, 0, stream>>>(x, props, out);
}